// Round 8
// baseline (1079.495 us; speedup 1.0000x reference)
//
#include <hip/hip_runtime.h>

typedef unsigned int u32;
typedef __attribute__((ext_vector_type(8))) short short8;
typedef __attribute__((ext_vector_type(4))) short short4v;
typedef __attribute__((ext_vector_type(4))) float f32x4;

__device__ __forceinline__ float lrelu(float x){ return x > 0.f ? x : 0.2f*x; }

// lgkm-only barrier: make LDS visible across waves WITHOUT draining vmcnt
// (atomics/loads keep flying; __syncthreads would force vmcnt(0) = full atomic drain)
#define BAR_LGKM() do { asm volatile("s_waitcnt lgkmcnt(0)" ::: "memory"); \
                        __builtin_amdgcn_s_barrier(); } while(0)

// float atomic max via sign-split (dest init -inf)
__device__ __forceinline__ void atomicMaxF(float* a, float v){
  if (__float_as_int(v) >= 0) atomicMax((int*)a, __float_as_int(v));
  else                        atomicMin((u32*)a, __float_as_uint(v));
}

__global__ void init_ws(float* __restrict__ nf1, float* __restrict__ nf2, int n32){
  int i = blockIdx.x*blockDim.x + threadIdx.x;
  int st = gridDim.x*blockDim.x;
  for (; i < n32; i += st){ nf1[i] = 0.f; nf2[i] = -__builtin_inff(); }
}

// RNE split: x = bf16(hi) + bf16(lo) + O(2^-18 x).
struct HL { short hi, lo; };
__device__ __forceinline__ HL split1(float x){
  u32 u = __float_as_uint(x);
  u32 r = u + 0x7FFFu + ((u >> 16) & 1u);
  float l = x - __uint_as_float(r & 0xFFFF0000u);
  HL o; o.hi = (short)(r >> 16); o.lo = (short)(__float_as_uint(l) >> 16);
  return o;
}

// one-time gather of a B fragment (W row-major [K][Nout], f32) with zero-fill OOB
__device__ __forceinline__ void gatherB(const float* __restrict__ W, int K, int Nout,
                                        int kbase, int n, short8& hi, short8& lo){
  #pragma unroll
  for (int j = 0; j < 8; ++j){
    int k = kbase + j;
    float w = (k < K && n < Nout) ? W[(size_t)k * Nout + n] : 0.f;
    HL s = split1(w); hi[j] = s.hi; lo[j] = s.lo;
  }
}

// 3-product accurate bf16 MFMA: D += Ah*Bh + Al*Bh + Ah*Bl
__device__ __forceinline__ f32x4 mfma3(short8 ah, short8 al, short8 bh, short8 bl, f32x4 c){
  c = __builtin_amdgcn_mfma_f32_16x16x32_bf16(ah, bh, c, 0, 0, 0);
  c = __builtin_amdgcn_mfma_f32_16x16x32_bf16(al, bh, c, 0, 0, 0);
  c = __builtin_amdgcn_mfma_f32_16x16x32_bf16(ah, bl, c, 0, 0, 0);
  return c;
}

// pre-split stores: split once at producer, consumers ds_read_b128 hi/lo planes directly
__device__ __forceinline__ void sstore1(short* hp, short* lp, int idx, float x){
  HL s = split1(x); hp[idx] = s.hi; lp[idx] = s.lo;
}
__device__ __forceinline__ void sstore4(short* hp, short* lp, int idx, f32x4 v){
  short4v h, l;
  #pragma unroll
  for (int j = 0; j < 4; ++j){ HL s = split1(v[j]); h[j] = s.hi; l[j] = s.lo; }
  *(short4v*)(hp + idx) = h;
  *(short4v*)(lp + idx) = l;
}

// ---------------- node_pre: P[n] = [ nf[n]·Wm1[0:64] | nf[n]·Wm1[64:128] ] (f32) ----------
__global__ __launch_bounds__(256, 2) void node_pre(
    const float* __restrict__ nf, const float* __restrict__ Wm1,
    float* __restrict__ P, int N)
{
  __shared__ short Xnh[32*72];
  __shared__ short Xnl[32*72];

  const int lane = threadIdx.x & 63, wv = threadIdx.x >> 6;
  const int nl = lane & 15, quad = lane >> 4;
  const int nb = wv;
  const int slot = wv*4 + quad;

  short8 Bah[2], Bal[2], Bbh[2], Bbl[2];
  #pragma unroll
  for (int kc = 0; kc < 2; ++kc){
    gatherB(Wm1, 144, 64, kc*32 + quad*8,      nb*16 + nl, Bah[kc], Bal[kc]);
    gatherB(Wm1, 144, 64, 64 + kc*32 + quad*8, nb*16 + nl, Bbh[kc], Bbl[kc]);
  }

  const int ntiles = (N + 31) >> 5;
  for (int t = blockIdx.x; t < ntiles; t += gridDim.x){
    const int base = t << 5;
    #pragma unroll
    for (int r2 = 0; r2 < 2; ++r2){
      int row = slot*2 + r2;
      int n = base + row;
      int nc = n < N ? n : 0;
      f32x4 v = *(const f32x4*)(nf + (size_t)nc*64 + nl*4);
      sstore4(Xnh, Xnl, row*72 + nl*4, v);
    }
    __syncthreads();

    f32x4 aa[2] = {{0,0,0,0},{0,0,0,0}};
    f32x4 ab[2] = {{0,0,0,0},{0,0,0,0}};
    #pragma unroll
    for (int kc = 0; kc < 2; ++kc)
      #pragma unroll
      for (int mb = 0; mb < 2; ++mb){
        int ro = (mb*16 + nl)*72 + kc*32 + quad*8;
        short8 ah = *(const short8*)(Xnh + ro);
        short8 al = *(const short8*)(Xnl + ro);
        aa[mb] = mfma3(ah, al, Bah[kc], Bal[kc], aa[mb]);
        ab[mb] = mfma3(ah, al, Bbh[kc], Bbl[kc], ab[mb]);
      }
    #pragma unroll
    for (int mb = 0; mb < 2; ++mb)
      #pragma unroll
      for (int r = 0; r < 4; ++r){
        int n = base + mb*16 + quad*4 + r;
        if (n < N){
          P[(size_t)n*128 +      nb*16 + nl] = aa[mb][r];
          P[(size_t)n*128 + 64 + nb*16 + nl] = ab[mb][r];
        }
      }
    __syncthreads();
  }
}

// ---- P-path edge kernel LDS geometry (shorts), parity-buffered Xe/S/H1/dstI ----
#define PXES  40            // ef planes stride: 16 real cols + 16 zero-pad
#define PSS   68            // S stride in f32
#define PH1S  72
#define PH2S  136
#define POFF_XEH  0         // Xeh[2]: q*1280
#define POFF_XEL  2560      // Xel[2]: q*1280
#define POFF_S    5120      // f32 S[2][32*68] = 2*2176 floats = 8704 shorts
#define POFF_H1H  13824     // H1h[2]: q*2304
#define POFF_H1L  18432     // H1l[2]: q*2304
#define POFF_H2H  23040     // 4352
#define POFF_H2L  27392     // 4352
#define POFF_DST  31744     // int dstI[2][32]
#define P_LDS_SHORTS 31872
#define P_LDS_BYTES  (P_LDS_SHORTS*2)   // 63744 B -> 2 blocks/CU (8 waves/CU)

// -------- P-path edge kernel: 32 edges/tile, 4 waves, 3 lgkm-only barriers/tile --------
// h1 = lrelu( S + ef·W1c + b1 ), S = P[src][0:64] + P[dst][64:128].
// T14 split staging: loads for tile t+stride ISSUE at loop top (hide under L1+L2);
// LDS-write lands after bar C (loads long returned); visibility via bar D.
// Atomics never drained in-loop (lgkm-only barriers).
// Race audit:
//   Xe/S[q]: last prior reader = L1 of the iteration with pp==q (ended before its bar B,
//            >=3 barriers ago); write at step (post-C) of iter t; next reader L1(t+1) after D(t). OK
//   dstI[q]: reader L4 runs after bar D with pp==q; writer (post-C of iter with pp==q^1...)
//            writes q=pp^1; bars D(t),B(t+1),C(t+1) separate from L4(t+1) read. OK
//   H1[q]: L1(t) w before B; L2(t) r before C; L3(t) w before D; L4(t) r after D;
//          next writer L1(t+2) after B(t+1). OK
//   H2: L2(t) w before C; L3(t) r before D; next writer L2(t+1) after B(t+1). OK
// NOTE: 256-thread blocks + launch_bounds(256,2) => 256-reg/wave budget; VGPR ~108+26
// prefetch regs fits. NEVER use 512-thread blocks with prefetch (r1: 128-reg cap -> spill).
__global__ __launch_bounds__(256, 2) void edge_mfma_p(
    const float* __restrict__ P, const float* __restrict__ ef,
    const int* __restrict__ src, const int* __restrict__ dst,
    const float* __restrict__ Wm1, const float* __restrict__ bm1,
    const float* __restrict__ Wm2, const float* __restrict__ bm2,
    const float* __restrict__ Wm3, const float* __restrict__ bm3,
    const float* __restrict__ Wm4, const float* __restrict__ bm4,
    float* __restrict__ nf1, float* __restrict__ nf2, int E)
{
  extern __shared__ short smem[];
  float* Sbase = (float*)(smem + POFF_S);
  int*   dstI  = (int*)(smem + POFF_DST);

  // one-time zero of Xe planes (pads 16..31 must stay 0; never aliased)
  {
    float* z = (float*)smem;
    for (int i = threadIdx.x; i < POFF_S/2; i += blockDim.x) z[i] = 0.f;
  }

  const int lane = threadIdx.x & 63, wv = threadIdx.x >> 6;
  const int nl = lane & 15, quad = lane >> 4;
  const int nb1 = wv;
  const int slot = wv*4 + quad;

  // ---- loop-invariant B fragments ----
  short8 B1ch, B1cl;
  gatherB(Wm1, 144, 64, 128 + quad*8, nb1*16 + nl, B1ch, B1cl);
  short8 B2h[2][2], B2l[2][2];
  #pragma unroll
  for (int i = 0; i < 2; ++i)
    #pragma unroll
    for (int kc = 0; kc < 2; ++kc) gatherB(Wm2, 64, 128, kc*32 + quad*8, (nb1 + i*4)*16 + nl, B2h[i][kc], B2l[i][kc]);
  short8 B3h[4], B3l[4];
  #pragma unroll
  for (int kc = 0; kc < 4; ++kc) gatherB(Wm3, 128, 64,  kc*32 + quad*8, nb1*16 + nl, B3h[kc], B3l[kc]);
  short8 B4h[2], B4l[2];
  #pragma unroll
  for (int kc = 0; kc < 2; ++kc) gatherB(Wm4, 64, 65, kc*32 + quad*8, nb1*16 + nl, B4h[kc], B4l[kc]);
  const int gcol = (nl < 8) ? 0 : 64;
  short8 Bgh[2], Bgl[2];
  #pragma unroll
  for (int kc = 0; kc < 2; ++kc) gatherB(Wm4, 64, 65, kc*32 + quad*8, gcol, Bgh[kc], Bgl[kc]);

  const float bi1  = bm1[nb1*16 + nl];
  const float bi2a = bm2[nb1*16 + nl], bi2b = bm2[(nb1+4)*16 + nl];
  const float bi3  = bm3[nb1*16 + nl];
  const float bi4a = bm4[nb1*16 + nl];
  const float big  = bm4[gcol];

  const int ntiles = (E + 31) >> 5;
  const int stride = gridDim.x;

  // prologue: stage tile blockIdx.x fully into parity 0
  __syncthreads();   // zeros visible (waves may still be in gatherB loads - full sync once)
  if (blockIdx.x < ntiles){
    short* xh = smem + POFF_XEH;
    short* xl = smem + POFF_XEL;
    #pragma unroll
    for (int r2 = 0; r2 < 2; ++r2){
      int row = slot*2 + r2;
      int e = (blockIdx.x << 5) + row;
      int ec = e < E ? e : 0;
      int s = src[ec], d = dst[ec];
      f32x4 a = *(const f32x4*)(P + (size_t)s*128 +      nl*4);
      f32x4 b = *(const f32x4*)(P + (size_t)d*128 + 64 + nl*4);
      *(f32x4*)(Sbase + row*PSS + nl*4) = a + b;
      if (nl < 4){
        f32x4 v2 = *(const f32x4*)(ef + (size_t)ec*16 + nl*4);
        sstore4(xh, xl, row*PXES + nl*4, v2);
      }
      if (nl == 5) dstI[row] = (e < E) ? d : -1;
    }
  }
  BAR_LGKM();

  int pp = 0;
  for (int t = blockIdx.x; t < ntiles; t += stride, pp ^= 1){
    short* xh  = smem + POFF_XEH + pp*1280;
    short* xl  = smem + POFF_XEL + pp*1280;
    float* sb  = Sbase + pp*2176;
    short* h1h = smem + POFF_H1H + pp*2304;
    short* h1l = smem + POFF_H1L + pp*2304;
    short* H2h = smem + POFF_H2H;
    short* H2l = smem + POFF_H2L;

    // ---- issue next-tile gathers into regs (latency hides under L1+L2) ----
    f32x4 pa[2], pb[2], pe2[2]; int pid[2];
    const int tn = t + stride;
    const bool havn = tn < ntiles;
    if (havn){
      #pragma unroll
      for (int r2 = 0; r2 < 2; ++r2){
        int row = slot*2 + r2;
        int e = (tn << 5) + row;
        int ec = e < E ? e : 0;
        int s = src[ec], d = dst[ec];
        pa[r2] = *(const f32x4*)(P + (size_t)s*128 +      nl*4);
        pb[r2] = *(const f32x4*)(P + (size_t)d*128 + 64 + nl*4);
        if (nl < 4) pe2[r2] = *(const f32x4*)(ef + (size_t)ec*16 + nl*4);
        pid[r2] = (e < E) ? d : -1;
      }
    }

    // ---- L1: K=32 ef-only + S epilogue add -> H1[pp] ----
    {
      f32x4 a1[2] = {{bi1,bi1,bi1,bi1},{bi1,bi1,bi1,bi1}};
      #pragma unroll
      for (int mb = 0; mb < 2; ++mb){
        int ro = (mb*16 + nl)*PXES + quad*8;
        short8 ah = *(const short8*)(xh + ro);
        short8 al = *(const short8*)(xl + ro);
        a1[mb] = mfma3(ah, al, B1ch, B1cl, a1[mb]);
      }
      #pragma unroll
      for (int mb = 0; mb < 2; ++mb)
        #pragma unroll
        for (int r = 0; r < 4; ++r){
          int row = mb*16 + quad*4 + r;
          float sv = sb[row*PSS + nb1*16 + nl];
          sstore1(h1h, h1l, row*PH1S + nb1*16 + nl, lrelu(a1[mb][r] + sv));
        }
    }
    BAR_LGKM();   // B: H1[pp] visible

    // ---- L2: K=64, dual n-block, H1[pp] -> H2 ----
    {
      f32x4 a2a[2] = {{bi2a,bi2a,bi2a,bi2a},{bi2a,bi2a,bi2a,bi2a}};
      f32x4 a2b[2] = {{bi2b,bi2b,bi2b,bi2b},{bi2b,bi2b,bi2b,bi2b}};
      #pragma unroll
      for (int kc = 0; kc < 2; ++kc)
        #pragma unroll
        for (int mb = 0; mb < 2; ++mb){
          int ro = (mb*16 + nl)*PH1S + kc*32 + quad*8;
          short8 ah = *(const short8*)(h1h + ro);
          short8 al = *(const short8*)(h1l + ro);
          a2a[mb] = mfma3(ah, al, B2h[0][kc], B2l[0][kc], a2a[mb]);
          a2b[mb] = mfma3(ah, al, B2h[1][kc], B2l[1][kc], a2b[mb]);
        }
      #pragma unroll
      for (int mb = 0; mb < 2; ++mb)
        #pragma unroll
        for (int r = 0; r < 4; ++r){
          int row = mb*16 + quad*4 + r;
          sstore1(H2h, H2l, row*PH2S + nb1*16 + nl,     lrelu(a2a[mb][r]));
          sstore1(H2h, H2l, row*PH2S + (nb1+4)*16 + nl, lrelu(a2b[mb][r]));
        }
    }
    BAR_LGKM();   // C: H2 visible (no VMEM dependency in this wait)

    // ---- stage-write tile tn into parity pp^1 (loads returned during L1+L2) ----
    if (havn){
      short* sxh = smem + POFF_XEH + (pp^1)*1280;
      short* sxl = smem + POFF_XEL + (pp^1)*1280;
      float* ssb = Sbase + (pp^1)*2176;
      #pragma unroll
      for (int r2 = 0; r2 < 2; ++r2){
        int row = slot*2 + r2;
        *(f32x4*)(ssb + row*PSS + nl*4) = pa[r2] + pb[r2];
        if (nl < 4) sstore4(sxh, sxl, row*PXES + nl*4, pe2[r2]);
        if (nl == 5) dstI[(pp^1)*32 + row] = pid[r2];
      }
    }

    // ---- L3: K=128, H2 -> H1[pp] (L2 reads of H1 done at C) ----
    {
      f32x4 a3[2] = {{bi3,bi3,bi3,bi3},{bi3,bi3,bi3,bi3}};
      #pragma unroll
      for (int kc = 0; kc < 4; ++kc)
        #pragma unroll
        for (int mb = 0; mb < 2; ++mb){
          int ro = (mb*16 + nl)*PH2S + kc*32 + quad*8;
          short8 ah = *(const short8*)(H2h + ro);
          short8 al = *(const short8*)(H2l + ro);
          a3[mb] = mfma3(ah, al, B3h[kc], B3l[kc], a3[mb]);
        }
      #pragma unroll
      for (int mb = 0; mb < 2; ++mb)
        #pragma unroll
        for (int r = 0; r < 4; ++r)
          sstore1(h1h, h1l, (mb*16 + quad*4 + r)*PH1S + nb1*16 + nl, lrelu(a3[mb][r]));
    }
    BAR_LGKM();   // D: H1[pp] + staged Xe/S/dstI[pp^1] visible

    // ---- L4 + scatter (fire-and-forget atomics; never drained in-loop) ----
    {
      f32x4 a4[2] = {{bi4a,bi4a,bi4a,bi4a},{bi4a,bi4a,bi4a,bi4a}};
      f32x4 ag[2] = {{big,big,big,big},{big,big,big,big}};
      #pragma unroll
      for (int kc = 0; kc < 2; ++kc)
        #pragma unroll
        for (int mb = 0; mb < 2; ++mb){
          int ro = (mb*16 + nl)*PH1S + kc*32 + quad*8;
          short8 ah = *(const short8*)(h1h + ro);
          short8 al = *(const short8*)(h1l + ro);
          a4[mb] = mfma3(ah, al, B4h[kc], B4l[kc], a4[mb]);
          ag[mb] = mfma3(ah, al, Bgh[kc], Bgl[kc], ag[mb]);
        }
      const int n = nb1*16 + nl;
      #pragma unroll
      for (int mb = 0; mb < 2; ++mb)
        #pragma unroll
        for (int r = 0; r < 4; ++r){
          int row = mb*16 + quad*4 + r;
          float glog = __shfl(ag[mb][r], lane & 0x30);
          float g = 1.f/(1.f + __expf(-glog));
          int d = dstI[pp*32 + row];
          if (d >= 0){
            float v = a4[mb][r] * g;
            if (n >= 1 && n <= 32)  atomicAdd(nf1 + (size_t)d*32 + (n-1), v);
            else if (n >= 33)       atomicMaxF(nf2 + (size_t)d*32 + (n-33), v);
            if (nb1 == 0 && nl == 8)
              atomicMaxF(nf2 + (size_t)d*32 + 31, ag[mb][r] * g);
          }
        }
    }
    // no tail barrier: next L1 reads Xe/S[pp^1] (visible since D) and writes H1[pp^1] (parity)
  }
}

// ---------------- fallback edge kernel (round-5, proven) -------------------------
#define XS   168
#define H1S  72
#define H2S  136
#define OFF_XL   5376
#define OFF_H2H  0
#define OFF_H2L  4352
#define OFF_H1H  10752
#define OFF_H1L  13056
#define OFF_DST  15360
#define LDS_SHORTS 15488
#define LDS_BYTES  (LDS_SHORTS*2)

__global__ __launch_bounds__(256, 2) void edge_mfma(
    const float* __restrict__ nf, const float* __restrict__ ef,
    const int* __restrict__ src, const int* __restrict__ dst,
    const float* __restrict__ Wm1, const float* __restrict__ bm1,
    const float* __restrict__ Wm2, const float* __restrict__ bm2,
    const float* __restrict__ Wm3, const float* __restrict__ bm3,
    const float* __restrict__ Wm4, const float* __restrict__ bm4,
    float* __restrict__ nf1, float* __restrict__ nf2, int E)
{
  extern __shared__ short smem[];
  short* Xh  = smem;
  short* Xl  = smem + OFF_XL;
  short* H2h = smem + OFF_H2H;
  short* H2l = smem + OFF_H2L;
  short* H1h = smem + OFF_H1H;
  short* H1l = smem + OFF_H1L;
  int*  dstI = (int*)(smem + OFF_DST);

  const int lane = threadIdx.x & 63, wv = threadIdx.x >> 6;
  const int nl = lane & 15, quad = lane >> 4;
  const int nb1 = wv;
  const int slot = wv*4 + quad;

  short8 B1h[5], B1l[5];
  #pragma unroll
  for (int kc = 0; kc < 5; ++kc) gatherB(Wm1, 144, 64,  kc*32 + quad*8, nb1*16 + nl, B1h[kc], B1l[kc]);
  short8 B2h[2][2], B2l[2][2];
  #pragma unroll
  for (int i = 0; i < 2; ++i)
    #pragma unroll
    for (int kc = 0; kc < 2; ++kc) gatherB(Wm2, 64, 128, kc*32 + quad*8, (nb1 + i*4)*16 + nl, B2h[i][kc], B2l[i][kc]);
  short8 B3h[4], B3l[4];
  #pragma unroll
  for (int kc = 0; kc < 4; ++kc) gatherB(Wm3, 128, 64,  kc*32 + quad*8, nb1*16 + nl, B3h[kc], B3l[kc]);
  short8 B4h[2], B4l[2];
  #pragma unroll
  for (int kc = 0; kc < 2; ++kc) gatherB(Wm4, 64, 65, kc*32 + quad*8, nb1*16 + nl, B4h[kc], B4l[kc]);
  const int gcol = (nl < 8) ? 0 : 64;
  short8 Bgh[2], Bgl[2];
  #pragma unroll
  for (int kc = 0; kc < 2; ++kc) gatherB(Wm4, 64, 65, kc*32 + quad*8, gcol, Bgh[kc], Bgl[kc]);

  const float bi1  = bm1[nb1*16 + nl];
  const float bi2a = bm2[nb1*16 + nl], bi2b = bm2[(nb1+4)*16 + nl];
  const float bi3  = bm3[nb1*16 + nl];
  const float bi4a = bm4[nb1*16 + nl];
  const float big  = bm4[gcol];

  const int ntiles = (E + 31) >> 5;
  int pp = 0;
  for (int t = blockIdx.x; t < ntiles; t += gridDim.x, pp ^= 1){
    #pragma unroll
    for (int r2 = 0; r2 < 2; ++r2){
      int row = slot*2 + r2;
      int e = (t << 5) + row;
      int ec = e < E ? e : 0;
      int s = src[ec], d = dst[ec];
      f32x4 v0 = *(const f32x4*)(nf + (size_t)s*64 + nl*4);
      f32x4 v1 = *(const f32x4*)(nf + (size_t)d*64 + nl*4);
      sstore4(Xh, Xl, row*XS + nl*4,      v0);
      sstore4(Xh, Xl, row*XS + 64 + nl*4, v1);
      if (nl < 4){
        f32x4 v2 = *(const f32x4*)(ef + (size_t)ec*16 + nl*4);
        sstore4(Xh, Xl, row*XS + 128 + nl*4, v2);
      } else if (nl < 8){
        short4v z = {0,0,0,0};
        *(short4v*)(Xh + row*XS + 144 + (nl-4)*4) = z;
        *(short4v*)(Xl + row*XS + 144 + (nl-4)*4) = z;
      }
      if (nl == 5) dstI[pp*32 + row] = (e < E) ? d : -1;
    }
    __syncthreads();

    {
      f32x4 a1[2] = {{bi1,bi1,bi1,bi1},{bi1,bi1,bi1,bi1}};
      #pragma unroll
      for (int kc = 0; kc < 5; ++kc)
        #pragma unroll
        for (int mb = 0; mb < 2; ++mb){
          int ro = (mb*16 + nl)*XS + kc*32 + quad*8;
          short8 ah = *(const short8*)(Xh + ro);
          short8 al = *(const short8*)(Xl + ro);
          a1[mb] = mfma3(ah, al, B1h[kc], B1l[kc], a1[mb]);
        }
      #pragma unroll
      for (int mb = 0; mb < 2; ++mb)
        #pragma unroll
        for (int r = 0; r < 4; ++r)
          sstore1(H1h, H1l, (mb*16 + quad*4 + r)*H1S + nb1*16 + nl, lrelu(a1[mb][r]));
    }
    __syncthreads();

    {
      f32x4 a2a[2] = {{bi2a,bi2a,bi2a,bi2a},{bi2a,bi2a,bi2a,bi2a}};
      f32x4 a2b[2] = {{bi2b,bi2b,bi2b,bi2b},{bi2b,bi2b,bi2b,bi2b}};
      #pragma unroll
      for (int kc = 0; kc < 2; ++kc)
        #pragma unroll
        for (int mb = 0; mb < 2; ++mb){
          int ro = (mb*16 + nl)*H1S + kc*32 + quad*8;
          short8 ah = *(const short8*)(H1h + ro);
          short8 al = *(const short8*)(H1l + ro);
          a2a[mb] = mfma3(ah, al, B2h[0][kc], B2l[0][kc], a2a[mb]);
          a2b[mb] = mfma3(ah, al, B2h[1][kc], B2l[1][kc], a2b[mb]);
        }
      #pragma unroll
      for (int mb = 0; mb < 2; ++mb)
        #pragma unroll
        for (int r = 0; r < 4; ++r){
          int row = mb*16 + quad*4 + r;
          sstore1(H2h, H2l, row*H2S + nb1*16 + nl,     lrelu(a2a[mb][r]));
          sstore1(H2h, H2l, row*H2S + (nb1+4)*16 + nl, lrelu(a2b[mb][r]));
        }
    }
    __syncthreads();

    {
      f32x4 a3[2] = {{bi3,bi3,bi3,bi3},{bi3,bi3,bi3,bi3}};
      #pragma unroll
      for (int kc = 0; kc < 4; ++kc)
        #pragma unroll
        for (int mb = 0; mb < 2; ++mb){
          int ro = (mb*16 + nl)*H2S + kc*32 + quad*8;
          short8 ah = *(const short8*)(H2h + ro);
          short8 al = *(const short8*)(H2l + ro);
          a3[mb] = mfma3(ah, al, B3h[kc], B3l[kc], a3[mb]);
        }
      #pragma unroll
      for (int mb = 0; mb < 2; ++mb)
        #pragma unroll
        for (int r = 0; r < 4; ++r)
          sstore1(H1h, H1l, (mb*16 + quad*4 + r)*H1S + nb1*16 + nl, lrelu(a3[mb][r]));
    }
    __syncthreads();

    {
      f32x4 a4[2] = {{bi4a,bi4a,bi4a,bi4a},{bi4a,bi4a,bi4a,bi4a}};
      f32x4 ag[2] = {{big,big,big,big},{big,big,big,big}};
      #pragma unroll
      for (int kc = 0; kc < 2; ++kc)
        #pragma unroll
        for (int mb = 0; mb < 2; ++mb){
          int ro = (mb*16 + nl)*H1S + kc*32 + quad*8;
          short8 ah = *(const short8*)(H1h + ro);
          short8 al = *(const short8*)(H1l + ro);
          a4[mb] = mfma3(ah, al, B4h[kc], B4l[kc], a4[mb]);
          ag[mb] = mfma3(ah, al, Bgh[kc], Bgl[kc], ag[mb]);
        }
      const int n = nb1*16 + nl;
      #pragma unroll
      for (int mb = 0; mb < 2; ++mb)
        #pragma unroll
        for (int r = 0; r < 4; ++r){
          int row = mb*16 + quad*4 + r;
          float glog = __shfl(ag[mb][r], lane & 0x30);
          float g = 1.f/(1.f + __expf(-glog));
          int d = dstI[pp*32 + row];
          if (d >= 0){
            float v = a4[mb][r] * g;
            if (n >= 1 && n <= 32)  atomicAdd(nf1 + (size_t)d*32 + (n-1), v);
            else if (n >= 33)       atomicMaxF(nf2 + (size_t)d*32 + (n-33), v);
            if (nb1 == 0 && nl == 8)
              atomicMaxF(nf2 + (size_t)d*32 + 31, ag[mb][r] * g);
          }
        }
    }
  }
}

__device__ void zero_f(float* p, int n){
  for (int i = threadIdx.x; i < n; i += blockDim.x) p[i] = 0.f;
}

#define B1S 68
#define C0S 132

__device__ __forceinline__ void splitA(const float* arow, int k0, short8& hi, short8& lo){
  f32x4 x0 = *(const f32x4*)(arow + k0);
  f32x4 x1 = *(const f32x4*)(arow + k0 + 4);
  #pragma unroll
  for (int j = 0; j < 4; ++j){
    HL a = split1(x0[j]); hi[j]   = a.hi; lo[j]   = a.lo;
    HL b = split1(x1[j]); hi[4+j] = b.hi; lo[4+j] = b.lo;
  }
}

// -------- node kernel: 32 nodes per block-tile, 8 waves (unchanged) --------
__global__ __launch_bounds__(512, 2) void node_mfma(
    const float* __restrict__ nf,
    const float* __restrict__ nf1, const float* __restrict__ nf2,
    const float* __restrict__ Wr1, const float* __restrict__ br1,
    const float* __restrict__ Wr2, const float* __restrict__ br2,
    const float* __restrict__ Wr3, const float* __restrict__ br3,
    const float* __restrict__ Wr4, const float* __restrict__ br4,
    float* __restrict__ out, int N)
{
  __shared__ float buf0[32*C0S];
  __shared__ float buf1[32*B1S];

  zero_f(buf0, 32*C0S);
  zero_f(buf1, 32*B1S);

  const int lane = threadIdx.x & 63, wv = threadIdx.x >> 6;
  const int nl = lane & 15, quad = lane >> 4;
  const int m = wv >> 2, nb = wv & 3;

  short8 B1h[4], B1l[4];
  #pragma unroll
  for (int kc = 0; kc < 4; ++kc) gatherB(Wr1, 128, 64,  kc*32 + quad*8, nb*16 + nl, B1h[kc], B1l[kc]);
  short8 B2h[2][2], B2l[2][2];
  #pragma unroll
  for (int i = 0; i < 2; ++i)
    #pragma unroll
    for (int kc = 0; kc < 2; ++kc) gatherB(Wr2, 64, 128, kc*32 + quad*8, (nb + i*4)*16 + nl, B2h[i][kc], B2l[i][kc]);
  short8 B3h[4], B3l[4];
  #pragma unroll
  for (int kc = 0; kc < 4; ++kc) gatherB(Wr3, 128, 64,  kc*32 + quad*8, nb*16 + nl, B3h[kc], B3l[kc]);
  short8 B4h[2], B4l[2];
  #pragma unroll
  for (int kc = 0; kc < 2; ++kc) gatherB(Wr4, 64, 64,   kc*32 + quad*8, nb*16 + nl, B4h[kc], B4l[kc]);

  const float bi1  = br1[nb*16 + nl];
  const float bi2a = br2[nb*16 + nl], bi2b = br2[(nb+4)*16 + nl];
  const float bi3  = br3[nb*16 + nl];
  const float bi4  = br4[nb*16 + nl];
  __syncthreads();

  const int ntiles = (N + 31) >> 5;
  for (int t = blockIdx.x; t < ntiles; t += gridDim.x){
    const int base = t << 5;
    {
      int row = wv*4 + quad;
      int n = base + row;
      int nc = n < N ? n : 0;
      *(f32x4*)(buf0 + row*C0S + nl*4) = *(const f32x4*)(nf + (size_t)nc*64 + nl*4);
      if (nl < 8){
        *(f32x4*)(buf0 + row*C0S + 64 + nl*4) = *(const f32x4*)(nf1 + (size_t)nc*32 + nl*4);
      } else {
        f32x4 v = *(const f32x4*)(nf2 + (size_t)nc*32 + (nl-8)*4);
        #pragma unroll
        for (int j = 0; j < 4; ++j) if (!(v[j] >= -3.0e38f)) v[j] = 0.f;
        *(f32x4*)(buf0 + row*C0S + 96 + (nl-8)*4) = v;
      }
    }
    __syncthreads();

    f32x4 a1 = {bi1, bi1, bi1, bi1};
    {
      const float* arow = buf0 + (m*16 + nl)*C0S;
      #pragma unroll
      for (int kc = 0; kc < 4; ++kc){
        short8 ah, al; splitA(arow, kc*32 + quad*8, ah, al);
        a1 = mfma3(ah, al, B1h[kc], B1l[kc], a1);
      }
    }
    #pragma unroll
    for (int r = 0; r < 4; ++r)
      buf1[(m*16 + quad*4 + r)*B1S + nb*16 + nl] = lrelu(a1[r]);
    __syncthreads();

    f32x4 a2a = {bi2a, bi2a, bi2a, bi2a}, a2b = {bi2b, bi2b, bi2b, bi2b};
    {
      const float* arow = buf1 + (m*16 + nl)*B1S;
      #pragma unroll
      for (int kc = 0; kc < 2; ++kc){
        short8 ah, al; splitA(arow, kc*32 + quad*8, ah, al);
        a2a = mfma3(ah, al, B2h[0][kc], B2l[0][kc], a2a);
        a2b = mfma3(ah, al, B2h[1][kc], B2l[1][kc], a2b);
      }
    }
    #pragma unroll
    for (int r = 0; r < 4; ++r){
      buf0[(m*16 + quad*4 + r)*C0S + nb*16 + nl]     = lrelu(a2a[r]);
      buf0[(m*16 + quad*4 + r)*C0S + (nb+4)*16 + nl] = lrelu(a2b[r]);
    }
    __syncthreads();

    f32x4 a3 = {bi3, bi3, bi3, bi3};
    {
      const float* arow = buf0 + (m*16 + nl)*C0S;
      #pragma unroll
      for (int kc = 0; kc < 4; ++kc){
        short8 ah, al; splitA(arow, kc*32 + quad*8, ah, al);
        a3 = mfma3(ah, al, B3h[kc], B3l[kc], a3);
      }
    }
    #pragma unroll
    for (int r = 0; r < 4; ++r)
      buf1[(m*16 + quad*4 + r)*B1S + nb*16 + nl] = lrelu(a3[r]);
    __syncthreads();

    f32x4 a4 = {bi4, bi4, bi4, bi4};
    {
      const float* arow = buf1 + (m*16 + nl)*B1S;
      #pragma unroll
      for (int kc = 0; kc < 2; ++kc){
        short8 ah, al; splitA(arow, kc*32 + quad*8, ah, al);
        a4 = mfma3(ah, al, B4h[kc], B4l[kc], a4);
      }
    }
    #pragma unroll
    for (int r = 0; r < 4; ++r){
      int n = base + m*16 + quad*4 + r;
      if (n < N) out[(size_t)n*64 + nb*16 + nl] = a4[r];
    }
  }
}

extern "C" void kernel_launch(void* const* d_in, const int* in_sizes, int n_in,
                              void* d_out, int out_size, void* d_ws, size_t ws_size,
                              hipStream_t stream) {
  const float* nf  = (const float*)d_in[0];
  const float* ef  = (const float*)d_in[1];
  const int*   src = (const int*)d_in[2];
  const int*   dst = (const int*)d_in[3];

  const int N = in_sizes[0] / 64;
  const int E = in_sizes[2];

  float* nf1 = (float*)d_ws;               // [N,32] segment-sum
  float* nf2 = nf1 + (size_t)N * 32;       // [N,32] segment-max
  float* P   = nf2 + (size_t)N * 32;       // [N,128] node-precomputed L1 partials

  size_t need = (size_t)N * 64 * 4 + (size_t)N * 128 * 4;
  bool useP = (ws_size >= need);

  static bool attr_set = false;
  if (!attr_set){
    hipFuncSetAttribute((const void*)edge_mfma,
                        hipFuncAttributeMaxDynamicSharedMemorySize, LDS_BYTES);
    hipFuncSetAttribute((const void*)edge_mfma_p,
                        hipFuncAttributeMaxDynamicSharedMemorySize, P_LDS_BYTES);
    attr_set = true;
  }

  init_ws<<<2048, 256, 0, stream>>>(nf1, nf2, N * 32);

  if (useP){
    node_pre<<<1024, 256, 0, stream>>>(nf, (const float*)d_in[4], P, N);
    edge_mfma_p<<<2048, 256, P_LDS_BYTES, stream>>>(
        P, ef, src, dst,
        (const float*)d_in[4],  (const float*)d_in[5],  (const float*)d_in[6],  (const float*)d_in[7],
        (const float*)d_in[8],  (const float*)d_in[9],  (const float*)d_in[10], (const float*)d_in[11],
        nf1, nf2, E);
  } else {
    edge_mfma<<<2048, 256, LDS_BYTES, stream>>>(
        nf, ef, src, dst,
        (const float*)d_in[4],  (const float*)d_in[5],  (const float*)d_in[6],  (const float*)d_in[7],
        (const float*)d_in[8],  (const float*)d_in[9],  (const float*)d_in[10], (const float*)d_in[11],
        nf1, nf2, E);
  }

  node_mfma<<<512, 512, 0, stream>>>(
      nf, nf1, nf2,
      (const float*)d_in[12], (const float*)d_in[13], (const float*)d_in[14], (const float*)d_in[15],
      (const float*)d_in[16], (const float*)d_in[17], (const float*)d_in[18], (const float*)d_in[19],
      (float*)d_out, N);
}